// Round 1
// baseline (1005.419 us; speedup 1.0000x reference)
//
#include <hip/hip_runtime.h>
#include <hip/hip_bf16.h>

// Problem constants (verified against in_sizes at launch where cheap)
#define D_HID 128
#define D_OUT 100
#define BN_EPS 1e-5f

// ---------------- helpers ----------------
__device__ __forceinline__ unsigned fmap(float f) {
    unsigned u = __float_as_uint(f);
    return (u & 0x80000000u) ? ~u : (u | 0x80000000u);
}
__device__ __forceinline__ float funmap(unsigned u) {
    return __uint_as_float((u & 0x80000000u) ? (u ^ 0x80000000u) : ~u);
}
#define NEG_INF_MAPPED 0x007FFFFFu  // fmap(-inf)

// ---------------- init ----------------
__global__ __launch_bounds__(256) void init_k(float* deg, unsigned* pool, float* bnsum,
                                              float* bnsq, int N, int P) {
    int i = blockIdx.x * 256 + threadIdx.x;
    if (i < N) deg[i] = 1.0f;               // self-loop contributes 1 to degree
    if (i < P) pool[i] = NEG_INF_MAPPED;
    if (i < 128) { bnsum[i] = 0.f; bnsq[i] = 0.f; }
}

__global__ __launch_bounds__(256) void deg_edge_k(const int* __restrict__ dst, float* deg, int E) {
    int e = blockIdx.x * 256 + threadIdx.x;
    if (e < E) atomicAdd(&deg[dst[e]], 1.0f);
}

__global__ __launch_bounds__(256) void dinv_k(float* deg, int N) {
    int i = blockIdx.x * 256 + threadIdx.x;
    if (i < N) deg[i] = rsqrtf(deg[i]);     // in-place: deg -> dinv
}

// ---------------- GEMM1: H = X @ W1  (f32, 64x128 tile) ----------------
#define BM 64
#define BK 32
__global__ __launch_bounds__(256) void gemm1_k(const float* __restrict__ X,
                                               const float* __restrict__ W,
                                               float* __restrict__ H, int N) {
    __shared__ float Xs[BK][BM];
    __shared__ float Ws[BK][128];
    int tid = threadIdx.x;
    int row0 = blockIdx.x * BM;
    int tx = tid & 31, ty = tid >> 5;
    float acc[8][4] = {};
    for (int k0 = 0; k0 < 128; k0 += BK) {
        {
            int kk = tid & 31, rb = tid >> 5;
            for (int j = 0; j < 8; ++j) {
                int r = rb + 8 * j, row = row0 + r;
                Xs[kk][r] = (row < N) ? X[row * 128 + k0 + kk] : 0.f;
            }
        }
        {
            int c = tid & 127, kb = tid >> 7;
            for (int j = 0; j < 16; ++j) {
                int kk = kb + 2 * j;
                Ws[kk][c] = W[(k0 + kk) * 128 + c];
            }
        }
        __syncthreads();
        for (int kk = 0; kk < BK; ++kk) {
            float4 w = *(const float4*)&Ws[kk][tx * 4];
            float x[8];
            *(float4*)&x[0] = *(const float4*)&Xs[kk][ty * 8];
            *(float4*)&x[4] = *(const float4*)&Xs[kk][ty * 8 + 4];
#pragma unroll
            for (int r = 0; r < 8; ++r) {
                acc[r][0] += x[r] * w.x; acc[r][1] += x[r] * w.y;
                acc[r][2] += x[r] * w.z; acc[r][3] += x[r] * w.w;
            }
        }
        __syncthreads();
    }
    for (int r = 0; r < 8; ++r) {
        int row = row0 + ty * 8 + r;
        if (row < N) *(float4*)&H[row * 128 + tx * 4] = *(float4*)&acc[r][0];
    }
}

// ---------------- aggregation layer 1 (128 wide) ----------------
__global__ __launch_bounds__(256) void agg_self128_k(const float* __restrict__ H,
                                                     const float* __restrict__ dinv,
                                                     float* __restrict__ X1, long long total) {
    long long i = (long long)blockIdx.x * 256 + threadIdx.x;
    if (i < total) {
        int row = (int)(i >> 7);
        float d = dinv[row];
        X1[i] = H[i] * d * d;
    }
}

__global__ __launch_bounds__(256) void agg_edge128_k(const float* __restrict__ H,
                                                     const int* __restrict__ src,
                                                     const int* __restrict__ dst,
                                                     const float* __restrict__ dinv,
                                                     float* __restrict__ X1, int E) {
    long long t = (long long)blockIdx.x * 256 + threadIdx.x;
    int e = (int)(t >> 7), f = (int)(t & 127);
    if (e >= E) return;
    int s = src[e], d = dst[e];
    float nrm = dinv[s] * dinv[d];
    atomicAdd(&X1[(long long)d * 128 + f], H[(long long)s * 128 + f] * nrm);
}

// ---------------- BN stats ----------------
__global__ __launch_bounds__(256) void bnstats_k(const float* __restrict__ X1,
                                                 float* bnsum, float* bnsq, int N) {
    int c = threadIdx.x & 127, half = threadIdx.x >> 7;
    float s = 0.f, q = 0.f;
    for (int row = blockIdx.x * 2 + half; row < N; row += gridDim.x * 2) {
        float v = X1[(long long)row * 128 + c];
        s += v; q += v * v;
    }
    __shared__ float ls[256], lq[256];
    ls[threadIdx.x] = s; lq[threadIdx.x] = q;
    __syncthreads();
    if (half == 0) {
        atomicAdd(&bnsum[c], s + ls[threadIdx.x + 128]);
        atomicAdd(&bnsq[c], q + lq[threadIdx.x + 128]);
    }
}

__global__ __launch_bounds__(128) void bnfinal_k(const float* bnsum, const float* bnsq,
                                                 const float* __restrict__ gamma,
                                                 const float* __restrict__ beta,
                                                 float* scale, float* shift, int N) {
    int c = threadIdx.x;
    float mu = bnsum[c] / (float)N;
    float var = bnsq[c] / (float)N - mu * mu;
    var = var > 0.f ? var : 0.f;
    float sc = gamma[c] * rsqrtf(var + BN_EPS);
    scale[c] = sc;
    shift[c] = beta[c] - mu * sc;
}

// ---------------- GEMM2: H2 = relu(BN(X1)) @ W2  (fused input transform) ----------------
__global__ __launch_bounds__(256) void gemm2_k(const float* __restrict__ X1,
                                               const float* __restrict__ W2,
                                               const float* __restrict__ scale,
                                               const float* __restrict__ shift,
                                               float* __restrict__ H2, int N) {
    __shared__ float Xs[BK][BM];
    __shared__ float Ws[BK][128];
    int tid = threadIdx.x;
    int row0 = blockIdx.x * BM;
    int tx = tid & 31, ty = tid >> 5;
    float acc[8][4] = {};
    for (int k0 = 0; k0 < 128; k0 += BK) {
        {
            int kk = tid & 31, rb = tid >> 5;
            float sc = scale[k0 + kk], sh = shift[k0 + kk];
            for (int j = 0; j < 8; ++j) {
                int r = rb + 8 * j, row = row0 + r;
                float v = (row < N) ? X1[(long long)row * 128 + k0 + kk] : 0.f;
                v = v * sc + sh;
                Xs[kk][r] = v > 0.f ? v : 0.f;
            }
        }
        {
            int c = tid & 127, kb = tid >> 7;
            for (int j = 0; j < 16; ++j) {
                int kk = kb + 2 * j;
                Ws[kk][c] = (c < D_OUT) ? W2[(k0 + kk) * D_OUT + c] : 0.f;
            }
        }
        __syncthreads();
        for (int kk = 0; kk < BK; ++kk) {
            float4 w = *(const float4*)&Ws[kk][tx * 4];
            float x[8];
            *(float4*)&x[0] = *(const float4*)&Xs[kk][ty * 8];
            *(float4*)&x[4] = *(const float4*)&Xs[kk][ty * 8 + 4];
#pragma unroll
            for (int r = 0; r < 8; ++r) {
                acc[r][0] += x[r] * w.x; acc[r][1] += x[r] * w.y;
                acc[r][2] += x[r] * w.z; acc[r][3] += x[r] * w.w;
            }
        }
        __syncthreads();
    }
    int c = tx * 4;
    if (c < D_OUT) {  // c <= 96, c+3 <= 99: full float4 in-range; (row*100+c)%4==0
        for (int r = 0; r < 8; ++r) {
            int row = row0 + ty * 8 + r;
            if (row < N) *(float4*)&H2[(long long)row * D_OUT + c] = *(float4*)&acc[r][0];
        }
    }
}

// ---------------- aggregation layer 2 (100 wide) ----------------
__global__ __launch_bounds__(256) void agg_self100_k(const float* __restrict__ H2,
                                                     const float* __restrict__ dinv,
                                                     float* __restrict__ Z, int N) {
    int node = blockIdx.x * 2 + (threadIdx.x >> 7);
    int f = threadIdx.x & 127;
    if (node >= N || f >= D_OUT) return;
    float d = dinv[node];
    Z[(long long)node * D_OUT + f] = H2[(long long)node * D_OUT + f] * d * d;
}

__global__ __launch_bounds__(256) void agg_edge100_k(const float* __restrict__ H2,
                                                     const int* __restrict__ src,
                                                     const int* __restrict__ dst,
                                                     const float* __restrict__ dinv,
                                                     float* __restrict__ Z, int E) {
    long long t = (long long)blockIdx.x * 256 + threadIdx.x;
    int e = (int)(t >> 7), f = (int)(t & 127);
    if (e >= E || f >= D_OUT) return;
    int s = src[e], d = dst[e];
    float nrm = dinv[s] * dinv[d];
    atomicAdd(&Z[(long long)d * D_OUT + f], H2[(long long)s * D_OUT + f] * nrm);
}

// ---------------- pool: segment_max(Z + b2, batch) ----------------
__global__ __launch_bounds__(256) void pool_k(const float* __restrict__ Z,
                                              const int* __restrict__ batch,
                                              const float* __restrict__ b2,
                                              unsigned* __restrict__ pool, int N) {
    int node = blockIdx.x * 2 + (threadIdx.x >> 7);
    int f = threadIdx.x & 127;
    if (node >= N || f >= D_OUT) return;
    int g = batch[node];
    float v = Z[(long long)node * D_OUT + f] + b2[f];
    atomicMax(&pool[(long long)g * D_OUT + f], fmap(v));
}

__global__ __launch_bounds__(256) void pool_final_k(const unsigned* __restrict__ pool,
                                                    float* __restrict__ out, int P) {
    int i = blockIdx.x * 256 + threadIdx.x;
    if (i < P) out[i] = funmap(pool[i]);
}

// ---------------- launch ----------------
extern "C" void kernel_launch(void* const* d_in, const int* in_sizes, int n_in,
                              void* d_out, int out_size, void* d_ws, size_t ws_size,
                              hipStream_t stream) {
    const float* X     = (const float*)d_in[0];
    const int*   eidx  = (const int*)d_in[1];
    const int*   batch = (const int*)d_in[2];
    const float* W1    = (const float*)d_in[4];
    // d_in[5] = b1: cancels inside batch_norm (per-feature constant shift)
    const float* gamma = (const float*)d_in[6];
    const float* beta  = (const float*)d_in[7];
    const float* W2    = (const float*)d_in[8];
    const float* b2    = (const float*)d_in[9];

    const int N = in_sizes[0] / D_HID;     // 200000
    const int E = in_sizes[1] / 2;         // 600000
    const int P = out_size;                // num_graphs * 100
    const int* src = eidx;
    const int* dst = eidx + E;

    // workspace layout
    char* p = (char*)d_ws;
    auto alloc = [&](size_t bytes) { char* q = p; p += (bytes + 255) & ~(size_t)255; return q; };
    float*    dinv   = (float*)alloc((size_t)N * 4);           // deg -> dinv in-place
    float*    bnsum  = (float*)alloc(128 * 4);
    float*    bnsq   = (float*)alloc(128 * 4);
    float*    scale  = (float*)alloc(128 * 4);
    float*    shift  = (float*)alloc(128 * 4);
    unsigned* pool   = (unsigned*)alloc((size_t)P * 4);
    float*    A      = (float*)alloc((size_t)N * 128 * 4);     // h1, then h2 (stride 100)
    float*    B      = (float*)alloc((size_t)N * 128 * 4);     // x1, then z (stride 100)

    const int nblk_init = (P + 255) / 256;                    // P > N here
    init_k<<<nblk_init, 256, 0, stream>>>(dinv, pool, bnsum, bnsq, N, P);
    deg_edge_k<<<(E + 255) / 256, 256, 0, stream>>>(dst, dinv, E);
    dinv_k<<<(N + 255) / 256, 256, 0, stream>>>(dinv, N);

    gemm1_k<<<(N + BM - 1) / BM, 256, 0, stream>>>(X, W1, A, N);

    long long tot128 = (long long)N * 128;
    agg_self128_k<<<(int)((tot128 + 255) / 256), 256, 0, stream>>>(A, dinv, B, tot128);
    agg_edge128_k<<<(int)(((long long)E * 128 + 255) / 256), 256, 0, stream>>>(A, src, dst, dinv, B, E);

    bnstats_k<<<1024, 256, 0, stream>>>(B, bnsum, bnsq, N);
    bnfinal_k<<<1, 128, 0, stream>>>(bnsum, bnsq, gamma, beta, scale, shift, N);

    gemm2_k<<<(N + BM - 1) / BM, 256, 0, stream>>>(B, W2, scale, shift, A, N);

    agg_self100_k<<<(N + 1) / 2, 256, 0, stream>>>(A, dinv, B, N);
    agg_edge100_k<<<(int)(((long long)E * 128 + 255) / 256), 256, 0, stream>>>(A, src, dst, dinv, B, E);

    pool_k<<<(N + 1) / 2, 256, 0, stream>>>(B, batch, b2, pool, N);
    pool_final_k<<<(P + 255) / 256, 256, 0, stream>>>(pool, (float*)d_out, P);
}

// Round 2
// 633.819 us; speedup vs baseline: 1.5863x; 1.5863x over previous
//
#include <hip/hip_runtime.h>
#include <hip/hip_bf16.h>

#define D_HID 128
#define D_OUT 100
#define BN_EPS 1e-5f

// ---------------- helpers ----------------
__device__ __forceinline__ unsigned fmap(float f) {
    unsigned u = __float_as_uint(f);
    return (u & 0x80000000u) ? ~u : (u | 0x80000000u);
}
__device__ __forceinline__ float funmap(unsigned u) {
    return __uint_as_float((u & 0x80000000u) ? (u ^ 0x80000000u) : ~u);
}
#define NEG_INF_MAPPED 0x007FFFFFu  // fmap(-inf)

// ---------------- init ----------------
__global__ __launch_bounds__(256) void init_k(int* deg, int* cursor, unsigned* pool,
                                              float* bnsum, float* bnsq, int N, int P) {
    int i = blockIdx.x * 256 + threadIdx.x;
    if (i < N) { deg[i] = 0; cursor[i] = 0; }
    if (i < P) pool[i] = NEG_INF_MAPPED;
    if (i < 128) { bnsum[i] = 0.f; bnsq[i] = 0.f; }
}

__global__ __launch_bounds__(256) void deg_k(const int* __restrict__ dst, int* deg, int E) {
    int e = blockIdx.x * 256 + threadIdx.x;
    if (e < E) atomicAdd(&deg[dst[e]], 1);
}

// ---------------- exclusive scan over deg -> off (2-level) ----------------
#define SCAN_EPB 1024  // elements per block (256 threads x 4)
__global__ __launch_bounds__(256) void scan1_k(const int* __restrict__ deg, int* __restrict__ off,
                                               int* __restrict__ btot, int N) {
    __shared__ int ts[256];
    int base = blockIdx.x * SCAN_EPB + threadIdx.x * 4;
    int v[4];
    int s = 0;
#pragma unroll
    for (int j = 0; j < 4; ++j) { int idx = base + j; v[j] = (idx < N) ? deg[idx] : 0; s += v[j]; }
    ts[threadIdx.x] = s;
    __syncthreads();
    for (int d = 1; d < 256; d <<= 1) {
        int t = (threadIdx.x >= d) ? ts[threadIdx.x - d] : 0;
        __syncthreads();
        ts[threadIdx.x] += t;
        __syncthreads();
    }
    int excl = ts[threadIdx.x] - s;
#pragma unroll
    for (int j = 0; j < 4; ++j) { int idx = base + j; if (idx < N) off[idx] = excl; excl += v[j]; }
    if (threadIdx.x == 255) btot[blockIdx.x] = ts[255];
}

__global__ __launch_bounds__(256) void scan2_k(int* btot, int nb, int* off, int N, int E) {
    __shared__ int ts[256];
    int v = (threadIdx.x < nb) ? btot[threadIdx.x] : 0;
    ts[threadIdx.x] = v;
    __syncthreads();
    for (int d = 1; d < 256; d <<= 1) {
        int t = (threadIdx.x >= d) ? ts[threadIdx.x - d] : 0;
        __syncthreads();
        ts[threadIdx.x] += t;
        __syncthreads();
    }
    if (threadIdx.x < nb) btot[threadIdx.x] = ts[threadIdx.x] - v;  // exclusive
    if (threadIdx.x == 0) off[N] = E;
}

__global__ __launch_bounds__(256) void scan3_dinv_k(int* off, const int* __restrict__ btot,
                                                    const int* __restrict__ deg,
                                                    float* __restrict__ dinv, int N) {
    int i = blockIdx.x * 256 + threadIdx.x;
    if (i < N) {
        off[i] += btot[i / SCAN_EPB];
        dinv[i] = rsqrtf((float)(1 + deg[i]));  // +1 self-loop; deg>=1 always
    }
}

__global__ __launch_bounds__(256) void fill_k(const int* __restrict__ src, const int* __restrict__ dst,
                                              const int* __restrict__ off, int* cursor,
                                              int* __restrict__ csr, int E) {
    int e = blockIdx.x * 256 + threadIdx.x;
    if (e < E) {
        int d = dst[e];
        int p = atomicAdd(&cursor[d], 1);
        csr[off[d] + p] = src[e];
    }
}

// ---------------- GEMM1: H = X @ W1  (f32, 64x128 tile) ----------------
#define BM 64
#define BK 32
__global__ __launch_bounds__(256) void gemm1_k(const float* __restrict__ X,
                                               const float* __restrict__ W,
                                               float* __restrict__ H, int N) {
    __shared__ float Xs[BK][BM];
    __shared__ float Ws[BK][128];
    int tid = threadIdx.x;
    int row0 = blockIdx.x * BM;
    int tx = tid & 31, ty = tid >> 5;
    float acc[8][4] = {};
    for (int k0 = 0; k0 < 128; k0 += BK) {
        {
            int kk = tid & 31, rb = tid >> 5;
            for (int j = 0; j < 8; ++j) {
                int r = rb + 8 * j, row = row0 + r;
                Xs[kk][r] = (row < N) ? X[(long long)row * 128 + k0 + kk] : 0.f;
            }
        }
        {
            int c = tid & 127, kb = tid >> 7;
            for (int j = 0; j < 16; ++j) {
                int kk = kb + 2 * j;
                Ws[kk][c] = W[(k0 + kk) * 128 + c];
            }
        }
        __syncthreads();
        for (int kk = 0; kk < BK; ++kk) {
            float4 w = *(const float4*)&Ws[kk][tx * 4];
            float x[8];
            *(float4*)&x[0] = *(const float4*)&Xs[kk][ty * 8];
            *(float4*)&x[4] = *(const float4*)&Xs[kk][ty * 8 + 4];
#pragma unroll
            for (int r = 0; r < 8; ++r) {
                acc[r][0] += x[r] * w.x; acc[r][1] += x[r] * w.y;
                acc[r][2] += x[r] * w.z; acc[r][3] += x[r] * w.w;
            }
        }
        __syncthreads();
    }
    for (int r = 0; r < 8; ++r) {
        int row = row0 + ty * 8 + r;
        if (row < N) *(float4*)&H[(long long)row * 128 + tx * 4] = *(float4*)&acc[r][0];
    }
}

// ---------------- agg1: X1 = Dinv(A+I)Dinv H, fused BN stats ----------------
__global__ __launch_bounds__(256) void agg1_k(const float* __restrict__ H,
                                              const int* __restrict__ off,
                                              const int* __restrict__ csr,
                                              const float* __restrict__ dinv,
                                              float* __restrict__ X1,
                                              float* bnsum, float* bnsq,
                                              int N, int chunk) {
    int g = blockIdx.x * 2 + (threadIdx.x >> 7);
    int f = threadIdx.x & 127;
    int n0 = g * chunk;
    int n1 = n0 + chunk; if (n1 > N) n1 = N;
    float bs = 0.f, bq = 0.f;
    for (int n = n0; n < n1; ++n) {
        float dn = dinv[n];
        float acc = dn * dn * H[(long long)n * 128 + f];
        int ie = off[n + 1];
        for (int i = off[n]; i < ie; ++i) {
            int s = csr[i];
            acc += dinv[s] * dn * H[(long long)s * 128 + f];
        }
        X1[(long long)n * 128 + f] = acc;
        bs += acc; bq += acc * acc;
    }
    __shared__ float ls[256], lq[256];
    ls[threadIdx.x] = bs; lq[threadIdx.x] = bq;
    __syncthreads();
    if (threadIdx.x < 128) {
        atomicAdd(&bnsum[f], ls[threadIdx.x] + ls[threadIdx.x + 128]);
        atomicAdd(&bnsq[f], lq[threadIdx.x] + lq[threadIdx.x + 128]);
    }
}

__global__ __launch_bounds__(128) void bnfinal_k(const float* bnsum, const float* bnsq,
                                                 const float* __restrict__ gamma,
                                                 const float* __restrict__ beta,
                                                 float* scale, float* shift, int N) {
    int c = threadIdx.x;
    float mu = bnsum[c] / (float)N;
    float var = bnsq[c] / (float)N - mu * mu;
    var = var > 0.f ? var : 0.f;
    float sc = gamma[c] * rsqrtf(var + BN_EPS);
    scale[c] = sc;
    shift[c] = beta[c] - mu * sc;
}

// ---------------- GEMM2: H2 = relu(BN(X1)) @ W2 ----------------
__global__ __launch_bounds__(256) void gemm2_k(const float* __restrict__ X1,
                                               const float* __restrict__ W2,
                                               const float* __restrict__ scale,
                                               const float* __restrict__ shift,
                                               float* __restrict__ H2, int N) {
    __shared__ float Xs[BK][BM];
    __shared__ float Ws[BK][128];
    int tid = threadIdx.x;
    int row0 = blockIdx.x * BM;
    int tx = tid & 31, ty = tid >> 5;
    float acc[8][4] = {};
    for (int k0 = 0; k0 < 128; k0 += BK) {
        {
            int kk = tid & 31, rb = tid >> 5;
            float sc = scale[k0 + kk], sh = shift[k0 + kk];
            for (int j = 0; j < 8; ++j) {
                int r = rb + 8 * j, row = row0 + r;
                float v = (row < N) ? X1[(long long)row * 128 + k0 + kk] : 0.f;
                v = v * sc + sh;
                Xs[kk][r] = v > 0.f ? v : 0.f;
            }
        }
        {
            int c = tid & 127, kb = tid >> 7;
            for (int j = 0; j < 16; ++j) {
                int kk = kb + 2 * j;
                Ws[kk][c] = (c < D_OUT) ? W2[(k0 + kk) * D_OUT + c] : 0.f;
            }
        }
        __syncthreads();
        for (int kk = 0; kk < BK; ++kk) {
            float4 w = *(const float4*)&Ws[kk][tx * 4];
            float x[8];
            *(float4*)&x[0] = *(const float4*)&Xs[kk][ty * 8];
            *(float4*)&x[4] = *(const float4*)&Xs[kk][ty * 8 + 4];
#pragma unroll
            for (int r = 0; r < 8; ++r) {
                acc[r][0] += x[r] * w.x; acc[r][1] += x[r] * w.y;
                acc[r][2] += x[r] * w.z; acc[r][3] += x[r] * w.w;
            }
        }
        __syncthreads();
    }
    int c = tx * 4;
    if (c < D_OUT) {
        for (int r = 0; r < 8; ++r) {
            int row = row0 + ty * 8 + r;
            if (row < N) *(float4*)&H2[(long long)row * D_OUT + c] = *(float4*)&acc[r][0];
        }
    }
}

// ---------------- agg2 + bias + segment_max pool (batch sorted) ----------------
__global__ __launch_bounds__(256) void agg2pool_k(const float* __restrict__ H2,
                                                  const int* __restrict__ off,
                                                  const int* __restrict__ csr,
                                                  const float* __restrict__ dinv,
                                                  const int* __restrict__ batch,
                                                  const float* __restrict__ b2,
                                                  unsigned* __restrict__ pool,
                                                  int N, int chunk) {
    int g = blockIdx.x * 2 + (threadIdx.x >> 7);
    int f = threadIdx.x & 127;
    if (f >= D_OUT) return;
    int n0 = g * chunk;
    int n1 = n0 + chunk; if (n1 > N) n1 = N;
    if (n0 >= n1) return;
    float bf = b2[f];
    int gcur = batch[n0];
    float vmax = -__builtin_inff();
    for (int n = n0; n < n1; ++n) {
        int gb = batch[n];
        if (gb != gcur) {
            atomicMax(&pool[(long long)gcur * D_OUT + f], fmap(vmax));
            gcur = gb;
            vmax = -__builtin_inff();
        }
        float dn = dinv[n];
        float acc = dn * dn * H2[(long long)n * D_OUT + f];
        int ie = off[n + 1];
        for (int i = off[n]; i < ie; ++i) {
            int s = csr[i];
            acc += dinv[s] * dn * H2[(long long)s * D_OUT + f];
        }
        float v = acc + bf;
        vmax = vmax > v ? vmax : v;
    }
    atomicMax(&pool[(long long)gcur * D_OUT + f], fmap(vmax));
}

__global__ __launch_bounds__(256) void pool_final_k(const unsigned* __restrict__ pool,
                                                    float* __restrict__ out, int P) {
    int i = blockIdx.x * 256 + threadIdx.x;
    if (i < P) out[i] = funmap(pool[i]);
}

// ---------------- launch ----------------
extern "C" void kernel_launch(void* const* d_in, const int* in_sizes, int n_in,
                              void* d_out, int out_size, void* d_ws, size_t ws_size,
                              hipStream_t stream) {
    const float* X     = (const float*)d_in[0];
    const int*   eidx  = (const int*)d_in[1];
    const int*   batch = (const int*)d_in[2];
    const float* W1    = (const float*)d_in[4];
    // d_in[5] = b1: cancels inside batch_norm (per-feature constant shift)
    const float* gamma = (const float*)d_in[6];
    const float* beta  = (const float*)d_in[7];
    const float* W2    = (const float*)d_in[8];
    const float* b2    = (const float*)d_in[9];

    const int N = in_sizes[0] / D_HID;     // 200000
    const int E = in_sizes[1] / 2;         // 600000
    const int P = out_size;                // num_graphs * 100
    const int* src = eidx;
    const int* dst = eidx + E;

    // workspace layout
    char* p = (char*)d_ws;
    auto alloc = [&](size_t bytes) { char* q = p; p += (bytes + 255) & ~(size_t)255; return q; };
    int*      deg    = (int*)alloc((size_t)N * 4);
    int*      cursor = (int*)alloc((size_t)N * 4);
    int*      off    = (int*)alloc((size_t)(N + 1) * 4);
    int*      btot   = (int*)alloc(256 * 4);
    int*      csr    = (int*)alloc((size_t)E * 4);
    float*    dinv   = (float*)alloc((size_t)N * 4);
    float*    bnsum  = (float*)alloc(128 * 4);
    float*    bnsq   = (float*)alloc(128 * 4);
    float*    scale  = (float*)alloc(128 * 4);
    float*    shift  = (float*)alloc(128 * 4);
    unsigned* pool   = (unsigned*)alloc((size_t)P * 4);
    float*    A      = (float*)alloc((size_t)N * 128 * 4);  // H (then H2, stride 100)
    float*    B      = (float*)alloc((size_t)N * 128 * 4);  // X1

    const int nb1 = (N + SCAN_EPB - 1) / SCAN_EPB;          // 196 <= 256
    const int initN = (N > P ? N : P);

    init_k<<<(initN + 255) / 256, 256, 0, stream>>>(deg, cursor, pool, bnsum, bnsq, N, P);
    deg_k<<<(E + 255) / 256, 256, 0, stream>>>(dst, deg, E);
    scan1_k<<<nb1, 256, 0, stream>>>(deg, off, btot, N);
    scan2_k<<<1, 256, 0, stream>>>(btot, nb1, off, N, E);
    scan3_dinv_k<<<(N + 255) / 256, 256, 0, stream>>>(off, btot, deg, dinv, N);
    fill_k<<<(E + 255) / 256, 256, 0, stream>>>(src, dst, off, cursor, csr, E);

    gemm1_k<<<(N + BM - 1) / BM, 256, 0, stream>>>(X, W1, A, N);

    const int nblk_agg = 2048;
    const int chunk = (N + nblk_agg * 2 - 1) / (nblk_agg * 2);
    agg1_k<<<nblk_agg, 256, 0, stream>>>(A, off, csr, dinv, B, bnsum, bnsq, N, chunk);
    bnfinal_k<<<1, 128, 0, stream>>>(bnsum, bnsq, gamma, beta, scale, shift, N);

    gemm2_k<<<(N + BM - 1) / BM, 256, 0, stream>>>(B, W2, scale, shift, A, N);

    agg2pool_k<<<nblk_agg, 256, 0, stream>>>(A, off, csr, dinv, batch, b2, pool, N, chunk);
    pool_final_k<<<(P + 255) / 256, 256, 0, stream>>>(pool, (float*)d_out, P);
}